// Round 3
// baseline (364.161 us; speedup 1.0000x reference)
//
#include <hip/hip_runtime.h>
#include <math.h>

// ---------------------------------------------------------------------------
// QuantumPoolingLayer — contiguous-slab pooling + tiny quantum kernel.
// inputs:  (128, 32, 32, 512) f32   [b][i][j][m], m contiguous
// weights: (512, 2, 4, 3) f32       [m][layer][k][{phi,theta,omega}]
// out:     (128, 512) f32           z = <Z_0>
//
// Kernel 1: grid = 128 b x 4 row-groups (8 rows each) = 512 blocks,
//   block = 512 threads = 128 float4-channel lanes x 4 row-workers.
//   Each block streams a fully contiguous 512 KB slab (8 rows x 32 j x 512 m).
//   Per-thread: 2 rows x 32 j float4 loads, split into qj<16 / qj>=16 sums.
//   LDS-reduce over the 4 row-workers -> ws[b][rg][qj][512] (2 MB total).
// Kernel 2: 65536 threads; reduce 2 row-groups per qi, tanh -> angles,
//   fully-unrolled 16-amplitude 4-qubit circuit, write z.
// ---------------------------------------------------------------------------

#define B_DIM   128
#define M_DIM   512
#define PI_F    3.14159265358979323846f

// ============================ Kernel 1: pooling ============================
__global__ __launch_bounds__(512)
void pool_kernel(const float* __restrict__ in, float* __restrict__ ws) {
    int blk = blockIdx.x;            // b*4 + rg
    int rg  = blk & 3;
    int b   = blk >> 2;
    int t   = threadIdx.x;
    int mc  = t & 127;               // float4 channel group (covers all 512 ch)
    int w   = t >> 7;                // row worker 0..3

    // rows i = rg*8 + w*2 + {0,1}; slab base for this block:
    const float4* base = (const float4*)in
        + ((size_t)b * 1024 + (size_t)rg * 8 * 32) * 128 + mc;

    float4 a0 = make_float4(0.f, 0.f, 0.f, 0.f);   // j < 16  (qj=0)
    float4 a1 = make_float4(0.f, 0.f, 0.f, 0.f);   // j >= 16 (qj=1)

    #pragma unroll
    for (int rr = 0; rr < 2; ++rr) {
        const float4* row = base + (size_t)(w * 2 + rr) * 32 * 128;
        #pragma unroll
        for (int j = 0; j < 32; ++j) {
            float4 v = row[(size_t)j * 128];
            if (j < 16) { a0.x += v.x; a0.y += v.y; a0.z += v.z; a0.w += v.w; }
            else        { a1.x += v.x; a1.y += v.y; a1.z += v.z; a1.w += v.w; }
        }
    }

    __shared__ float4 lds[4][2][128];   // 16 KiB
    lds[w][0][mc] = a0;
    lds[w][1][mc] = a1;
    __syncthreads();

    if (t < 256) {
        int qj = t >> 7, c = t & 127;
        float4 s0 = lds[0][qj][c], s1 = lds[1][qj][c];
        float4 s2 = lds[2][qj][c], s3 = lds[3][qj][c];
        float4 s;
        s.x = s0.x + s1.x + s2.x + s3.x;
        s.y = s0.y + s1.y + s2.y + s3.y;
        s.z = s0.z + s1.z + s2.z + s3.z;
        s.w = s0.w + s1.w + s2.w + s3.w;
        ((float4*)ws)[((size_t)blk * 2 + qj) * 128 + c] = s;
    }
}

// ========================= Kernel 2: quantum sim ===========================
struct Cpx { float x, y; };

template<int M>
__device__ __forceinline__ void apply1q(float* re, float* im,
                                        Cpx g00, Cpx g01, Cpx g10, Cpx g11) {
    #pragma unroll
    for (int s = 0; s < 16; ++s) {
        if (s & M) continue;
        int s1 = s | M;
        float ar = re[s],  ai = im[s];
        float br = re[s1], bi = im[s1];
        re[s]  = g00.x * ar - g00.y * ai + g01.x * br - g01.y * bi;
        im[s]  = g00.x * ai + g00.y * ar + g01.x * bi + g01.y * br;
        re[s1] = g10.x * ar - g10.y * ai + g11.x * br - g11.y * bi;
        im[s1] = g10.x * ai + g10.y * ar + g11.x * bi + g11.y * br;
    }
}

template<int MC, int MT>
__device__ __forceinline__ void cnot(float* re, float* im) {
    #pragma unroll
    for (int s = 0; s < 16; ++s) {
        if ((s & MC) && !(s & MT)) {
            int s1 = s | MT;
            float t;
            t = re[s]; re[s] = re[s1]; re[s1] = t;
            t = im[s]; im[s] = im[s1]; im[s1] = t;
        }
    }
}

__device__ __forceinline__ void rot_gate(float phi, float theta, float omega,
                                         Cpx& g00, Cpx& g01, Cpx& g10, Cpx& g11) {
    float st, ct, sa, ca, sd, cd;
    __sincosf(0.5f * theta, &st, &ct);
    __sincosf(0.5f * (phi + omega), &sa, &ca);
    __sincosf(0.5f * (phi - omega), &sd, &cd);
    g00.x =  ca * ct;  g00.y = -sa * ct;
    g01.x = -cd * st;  g01.y = -sd * st;
    g10.x =  cd * st;  g10.y = -sd * st;
    g11.x =  ca * ct;  g11.y =  sa * ct;
}

__global__ __launch_bounds__(256)
void quantum_kernel(const float* __restrict__ ws, const float* __restrict__ qw,
                    float* __restrict__ out) {
    int idx = blockIdx.x * 256 + threadIdx.x;   // 65536 threads
    int m = idx & (M_DIM - 1);
    int b = idx >> 9;

    float ang[4];
    #pragma unroll
    for (int qi = 0; qi < 2; ++qi) {
        #pragma unroll
        for (int qj = 0; qj < 2; ++qj) {
            float s = 0.f;
            #pragma unroll
            for (int rr = 0; rr < 2; ++rr) {
                int rg = qi * 2 + rr;
                s += ws[(((size_t)b * 4 + rg) * 2 + qj) * M_DIM + m];
            }
            ang[qi * 2 + qj] = tanhf(s * (1.0f / 256.0f)) * PI_F;
        }
    }

    // |0000> through RY(ang[k]) on wire k: real product state
    float cs[4], sn[4];
    #pragma unroll
    for (int k = 0; k < 4; ++k) __sincosf(0.5f * ang[k], &sn[k], &cs[k]);

    float re[16], im[16];
    #pragma unroll
    for (int s = 0; s < 16; ++s) {
        re[s] = ((s & 8) ? sn[0] : cs[0]) * ((s & 4) ? sn[1] : cs[1]) *
                ((s & 2) ? sn[2] : cs[2]) * ((s & 1) ? sn[3] : cs[3]);
        im[s] = 0.f;
    }

    const float* wbase = qw + (size_t)m * 24;   // [m][layer][k][3]
    #pragma unroll
    for (int layer = 0; layer < 2; ++layer) {
        const float* wl = wbase + layer * 12;
        Cpx g00, g01, g10, g11;
        rot_gate(wl[0],  wl[1],  wl[2],  g00, g01, g10, g11); apply1q<8>(re, im, g00, g01, g10, g11);
        rot_gate(wl[3],  wl[4],  wl[5],  g00, g01, g10, g11); apply1q<4>(re, im, g00, g01, g10, g11);
        rot_gate(wl[6],  wl[7],  wl[8],  g00, g01, g10, g11); apply1q<2>(re, im, g00, g01, g10, g11);
        rot_gate(wl[9],  wl[10], wl[11], g00, g01, g10, g11); apply1q<1>(re, im, g00, g01, g10, g11);
        cnot<8, 4>(re, im);
        cnot<8, 2>(re, im);
        cnot<8, 1>(re, im);
        cnot<4, 2>(re, im);
        cnot<4, 1>(re, im);
        cnot<2, 1>(re, im);
    }

    float z = 0.f;
    #pragma unroll
    for (int s = 0; s < 16; ++s) {
        float p = re[s] * re[s] + im[s] * im[s];
        z += (s & 8) ? -p : p;
    }
    out[idx] = z;
}

// ================================ launch ===================================
extern "C" void kernel_launch(void* const* d_in, const int* in_sizes, int n_in,
                              void* d_out, int out_size, void* d_ws, size_t ws_size,
                              hipStream_t stream) {
    const float* in = (const float*)d_in[0];   // (128,32,32,512) f32
    const float* qw = (const float*)d_in[1];   // (512,2,4,3) f32
    float* out = (float*)d_out;                // (128,512) f32
    float* ws  = (float*)d_ws;                 // 2 MiB of partials

    (void)in_sizes; (void)n_in; (void)out_size; (void)ws_size;

    pool_kernel<<<B_DIM * 4, 512, 0, stream>>>(in, ws);
    quantum_kernel<<<(B_DIM * M_DIM) / 256, 256, 0, stream>>>(ws, qw, out);
}